// Round 2
// baseline (436.810 us; speedup 1.0000x reference)
//
#include <hip/hip_runtime.h>

// FoldLayer (col2im overlap-add), uniform 2x2-block gather formulation.
//
// v6 = v5 with two changes:
//  (a) bit-exact accumulation order: contributions are added in the
//      reference's ascending slice order (i*3+j), with zero-initialized
//      temporaries for conditional contributions (x+0 is exact), restoring
//      absmax = 0.0 (v5's s8-first order showed absmax = 1 bf16-ulp).
//  (b) loads are plain (cached) instead of nontemporal; stores stay
//      nontemporal. No reuse exists, so nt-loads can only cost BW if the
//      nt path is slower than the normal path — this is the A/B test.
//
// Mapping (unchanged): one thread owns a 2x2 output pixel block for one
// float4 channel group, for batches b and b+8. The 9 contributions of a
// 2x2 block are exactly the 9 kernel slices of 4 patches:
//   patch (t,u):     slices 4,5,7,8   always valid
//   patch (t,u+1):   slices 3,6       valid if u<63
//   patch (t+1,u):   slices 1,2       valid if t<63
//   patch (t+1,u+1): slice  0         valid if both
// Pixel accumulation (ascending slice order = reference op order):
//   out(2t  ,2u  ) = s4
//   out(2t  ,2u+1) = s3' + s5
//   out(2t+1,2u  ) = s1'' + s7
//   out(2t+1,2u+1) = ((s0''' + s2'') + s6') + s8
// Branch-free in the interior (t<63 && u<63 covers 3969/4096 blocks, and
// both predicates are wave-uniform except 1/32 waves at the u edge).
//
// Shapes: patches (16, 64, 64, 9*128) fp32 kernel-major;
// out (16, 128, 128, 128) fp32.

#define GH 64
#define GW 64

typedef float v4f __attribute__((ext_vector_type(4)));

__global__ __launch_bounds__(256) void fold_block_kernel(
    const v4f* __restrict__ p, v4f* __restrict__ out) {
    const int PSTRIDE     = 288;                 // 3*3*128/4 float4 per patch
    const int ROWSTRIDE   = GW * PSTRIDE;        // float4 per patch row
    const int BSTRIDE_IN  = GH * GW * PSTRIDE;   // per-batch input float4
    const int BSTRIDE_OUT = 128 * 128 * 32;      // per-batch output float4

    int tid = blockIdx.x * 256 + threadIdx.x;
    int c4 = tid & 31;           // float4 channel group, 32 per pixel
    int bx = (tid >> 5) & 63;    // output 2x2-block col == patch col u
    int by = (tid >> 11) & 63;   // output 2x2-block row == patch row t
    int b  = tid >> 17;          // [0,8); partner batch is b+8

    bool tOk = (by < GH - 1);
    bool uOk = (bx < GW - 1);

    const v4f* q0 = p + ((b * GH + by) * GW + bx) * PSTRIDE + c4;  // patch (t,u), batch b
    const v4f* q1 = q0 + 8 * BSTRIDE_IN;                           // batch b+8

    // Unconditional loads: patch (t,u) slices 4,5,7,8, both batches.
    v4f l4 = q0[4 * 32];
    v4f l5 = q0[5 * 32];
    v4f l7 = q0[7 * 32];
    v4f l8 = q0[8 * 32];
    v4f m4 = q1[4 * 32];
    v4f m5 = q1[5 * 32];
    v4f m7 = q1[7 * 32];
    v4f m8 = q1[8 * 32];

    const v4f z = {0.f, 0.f, 0.f, 0.f};
    v4f l3 = z, l6 = z, m3 = z, m6 = z;   // patch (t,u+1)
    v4f l1 = z, l2 = z, m1 = z, m2 = z;   // patch (t+1,u)
    v4f l0 = z, m0 = z;                   // patch (t+1,u+1)

    if (uOk) {
        const v4f* r0 = q0 + PSTRIDE;
        const v4f* r1 = q1 + PSTRIDE;
        l3 = r0[3 * 32];
        l6 = r0[6 * 32];
        m3 = r1[3 * 32];
        m6 = r1[6 * 32];
    }
    if (tOk) {
        const v4f* r0 = q0 + ROWSTRIDE;
        const v4f* r1 = q1 + ROWSTRIDE;
        l1 = r0[1 * 32];
        l2 = r0[2 * 32];
        m1 = r1[1 * 32];
        m2 = r1[2 * 32];
        if (uOk) {
            l0 = r0[PSTRIDE];
            m0 = r1[PSTRIDE];
        }
    }

    // Reference-order accumulation (ascending slice index); zero temps make
    // the border cases bit-exact too.
    v4f a00 = l4;
    v4f a01 = l3 + l5;
    v4f a10 = l1 + l7;
    v4f a11 = ((l0 + l2) + l6) + l8;
    v4f c00 = m4;
    v4f c01 = m3 + m5;
    v4f c10 = m1 + m7;
    v4f c11 = ((m0 + m2) + m6) + m8;

    // Stores: pixels (2t,2u),(2t,2u+1),(2t+1,2u),(2t+1,2u+1), batches b, b+8.
    int o = ((b * 128 + 2 * by) * 128 + 2 * bx) * 32 + c4;
    v4f* w0 = out + o;
    v4f* w1 = w0 + 8 * BSTRIDE_OUT;
    __builtin_nontemporal_store(a00, w0);
    __builtin_nontemporal_store(a01, w0 + 32);
    __builtin_nontemporal_store(a10, w0 + 128 * 32);
    __builtin_nontemporal_store(a11, w0 + 128 * 32 + 32);
    __builtin_nontemporal_store(c00, w1);
    __builtin_nontemporal_store(c01, w1 + 32);
    __builtin_nontemporal_store(c10, w1 + 128 * 32);
    __builtin_nontemporal_store(c11, w1 + 128 * 32 + 32);
}

extern "C" void kernel_launch(void* const* d_in, const int* in_sizes, int n_in,
                              void* d_out, int out_size, void* d_ws, size_t ws_size,
                              hipStream_t stream) {
    const v4f* p = (const v4f*)d_in[0];
    v4f* out = (v4f*)d_out;
    // 8 batch-pairs x 64 x 64 blocks x 32 channel-groups = 1,048,576 threads
    dim3 block(256);
    dim3 grid(1048576 / 256);  // 4096 blocks
    fold_block_kernel<<<grid, block, 0, stream>>>(p, out);
}

// Round 3
// 407.576 us; speedup vs baseline: 1.0717x; 1.0717x over previous
//
#include <hip/hip_runtime.h>

// FoldLayer (col2im overlap-add), uniform 2x2-block gather formulation.
//
// v7 = best of measured A/B: v6's bit-exact ascending-slice accumulation
// (absmax 0.0) + v5's nontemporal LOADS (408.8 vs 436.8 us measured; the
// 299 MB read stream has zero reuse and exceeds L3, so bypassing cache
// allocation is a measured ~7% win). Stores stay nontemporal.
//
// Mapping: one thread owns a 2x2 output pixel block for one float4 channel
// group, for batches b and b+8. The 9 contributions of a 2x2 block are
// exactly the 9 kernel slices of 4 patches:
//   patch (t,u):     slices 4,5,7,8   always valid
//   patch (t,u+1):   slices 3,6       valid if u<63
//   patch (t+1,u):   slices 1,2       valid if t<63
//   patch (t+1,u+1): slice  0         valid if both
// Pixel accumulation (ascending slice order = reference op order, with
// zero-init temporaries so border cases are bit-exact too):
//   out(2t  ,2u  ) = s4
//   out(2t  ,2u+1) = s3' + s5
//   out(2t+1,2u  ) = s1'' + s7
//   out(2t+1,2u+1) = ((s0''' + s2'') + s6') + s8
// Branch-free in the interior (3969/4096 blocks; predicates wave-uniform
// except 1/32 waves at the u edge).
//
// Shapes: patches (16, 64, 64, 9*128) fp32 kernel-major;
// out (16, 128, 128, 128) fp32.

#define GH 64
#define GW 64

typedef float v4f __attribute__((ext_vector_type(4)));

__global__ __launch_bounds__(256) void fold_block_kernel(
    const v4f* __restrict__ p, v4f* __restrict__ out) {
    const int PSTRIDE     = 288;                 // 3*3*128/4 float4 per patch
    const int ROWSTRIDE   = GW * PSTRIDE;        // float4 per patch row
    const int BSTRIDE_IN  = GH * GW * PSTRIDE;   // per-batch input float4
    const int BSTRIDE_OUT = 128 * 128 * 32;      // per-batch output float4

    int tid = blockIdx.x * 256 + threadIdx.x;
    int c4 = tid & 31;           // float4 channel group, 32 per pixel
    int bx = (tid >> 5) & 63;    // output 2x2-block col == patch col u
    int by = (tid >> 11) & 63;   // output 2x2-block row == patch row t
    int b  = tid >> 17;          // [0,8); partner batch is b+8

    bool tOk = (by < GH - 1);
    bool uOk = (bx < GW - 1);

    const v4f* q0 = p + ((b * GH + by) * GW + bx) * PSTRIDE + c4;  // patch (t,u), batch b
    const v4f* q1 = q0 + 8 * BSTRIDE_IN;                           // batch b+8

    // Unconditional loads: patch (t,u) slices 4,5,7,8, both batches.
    v4f l4 = __builtin_nontemporal_load(q0 + 4 * 32);
    v4f l5 = __builtin_nontemporal_load(q0 + 5 * 32);
    v4f l7 = __builtin_nontemporal_load(q0 + 7 * 32);
    v4f l8 = __builtin_nontemporal_load(q0 + 8 * 32);
    v4f m4 = __builtin_nontemporal_load(q1 + 4 * 32);
    v4f m5 = __builtin_nontemporal_load(q1 + 5 * 32);
    v4f m7 = __builtin_nontemporal_load(q1 + 7 * 32);
    v4f m8 = __builtin_nontemporal_load(q1 + 8 * 32);

    const v4f z = {0.f, 0.f, 0.f, 0.f};
    v4f l3 = z, l6 = z, m3 = z, m6 = z;   // patch (t,u+1)
    v4f l1 = z, l2 = z, m1 = z, m2 = z;   // patch (t+1,u)
    v4f l0 = z, m0 = z;                   // patch (t+1,u+1)

    if (uOk) {
        const v4f* r0 = q0 + PSTRIDE;
        const v4f* r1 = q1 + PSTRIDE;
        l3 = __builtin_nontemporal_load(r0 + 3 * 32);
        l6 = __builtin_nontemporal_load(r0 + 6 * 32);
        m3 = __builtin_nontemporal_load(r1 + 3 * 32);
        m6 = __builtin_nontemporal_load(r1 + 6 * 32);
    }
    if (tOk) {
        const v4f* r0 = q0 + ROWSTRIDE;
        const v4f* r1 = q1 + ROWSTRIDE;
        l1 = __builtin_nontemporal_load(r0 + 1 * 32);
        l2 = __builtin_nontemporal_load(r0 + 2 * 32);
        m1 = __builtin_nontemporal_load(r1 + 1 * 32);
        m2 = __builtin_nontemporal_load(r1 + 2 * 32);
        if (uOk) {
            l0 = __builtin_nontemporal_load(r0 + PSTRIDE);
            m0 = __builtin_nontemporal_load(r1 + PSTRIDE);
        }
    }

    // Reference-order accumulation (ascending slice index); zero temps make
    // the border cases bit-exact too.
    v4f a00 = l4;
    v4f a01 = l3 + l5;
    v4f a10 = l1 + l7;
    v4f a11 = ((l0 + l2) + l6) + l8;
    v4f c00 = m4;
    v4f c01 = m3 + m5;
    v4f c10 = m1 + m7;
    v4f c11 = ((m0 + m2) + m6) + m8;

    // Stores: pixels (2t,2u),(2t,2u+1),(2t+1,2u),(2t+1,2u+1), batches b, b+8.
    int o = ((b * 128 + 2 * by) * 128 + 2 * bx) * 32 + c4;
    v4f* w0 = out + o;
    v4f* w1 = w0 + 8 * BSTRIDE_OUT;
    __builtin_nontemporal_store(a00, w0);
    __builtin_nontemporal_store(a01, w0 + 32);
    __builtin_nontemporal_store(a10, w0 + 128 * 32);
    __builtin_nontemporal_store(a11, w0 + 128 * 32 + 32);
    __builtin_nontemporal_store(c00, w1);
    __builtin_nontemporal_store(c01, w1 + 32);
    __builtin_nontemporal_store(c10, w1 + 128 * 32);
    __builtin_nontemporal_store(c11, w1 + 128 * 32 + 32);
}

extern "C" void kernel_launch(void* const* d_in, const int* in_sizes, int n_in,
                              void* d_out, int out_size, void* d_ws, size_t ws_size,
                              hipStream_t stream) {
    const v4f* p = (const v4f*)d_in[0];
    v4f* out = (v4f*)d_out;
    // 8 batch-pairs x 64 x 64 blocks x 32 channel-groups = 1,048,576 threads
    dim3 block(256);
    dim3 grid(1048576 / 256);  // 4096 blocks
    fold_block_kernel<<<grid, block, 0, stream>>>(p, out);
}